// Round 10
// baseline (941.073 us; speedup 1.0000x reference)
//
#include <hip/hip_runtime.h>
#include <cstdint>
#include <cstddef>

#define N_NODES  30000
#define N_EDGES  480000
#define N_LAYERS 3
#define N_GRAPHS 64
#define N_CLASS  10
#define NREP     32

typedef __attribute__((ext_vector_type(8))) short short8v;   // 8 bf16 (4 VGPR)
typedef __attribute__((ext_vector_type(4))) float f32x4;

__device__ __forceinline__ unsigned short f2bf(float x) {
  union { float f; unsigned u; } v; v.f = x;
  unsigned r = v.u + 0x7FFFu + ((v.u >> 16) & 1u);   // RNE
  return (unsigned short)(r >> 16);
}
__device__ __forceinline__ float bf2f(unsigned short h) {
  union { unsigned u; float f; } v; v.u = ((unsigned)h) << 16;
  return v.f;
}
// XOR-swizzle for the [128 rows x 256B] W tile (guide §6 G4).
__device__ __forceinline__ int swzW(int row, int off16) {
  return (row << 8) | (off16 ^ ((row & 7) << 4));
}

// ============ weight convert + transpose: Wt[mi][n][k] = bf16(W[k][n]) ======
__global__ void wconv(const float* __restrict__ Wh, const float* __restrict__ We,
                      const float* __restrict__ WA, const float* __restrict__ WB,
                      const float* __restrict__ WC, const float* __restrict__ WD,
                      const float* __restrict__ WE, unsigned short* __restrict__ Wt)
{
  const int mi  = blockIdx.x >> 6;
  const int idx = (blockIdx.x & 63) * 256 + threadIdx.x;   // 0..16383
  const float* src;
  if      (mi == 0) src = Wh;
  else if (mi == 1) src = We;
  else if (mi < 5)  src = WA + (size_t)(mi - 2) * 16384;
  else if (mi < 8)  src = WB + (size_t)(mi - 5) * 16384;
  else if (mi < 11) src = WC + (size_t)(mi - 8) * 16384;
  else if (mi < 14) src = WD + (size_t)(mi - 11) * 16384;
  else              src = WE + (size_t)(mi - 14) * 16384;
  const int k = idx >> 7, n = idx & 127;
  Wt[(size_t)mi * 16384 + (size_t)n * 128 + k] = f2bf(src[idx]);
}

// ============ node GEMM, one matrix per block (blockIdx.y = m) ==============
// AMODE 0: A = bf16 rows (plain)
// AMODE 1: A = hprev + relu(tbuf*P+Q); y==0 block writes hout (ping-pong)
// AMODE 2: CHAIN — A = bf16(h_in_fp32 @ WtX + biasX); y==0 writes hout
struct GemmArgs {
  const unsigned short* Wt[4];
  const float* bias[4];
  unsigned short* out[4];
};

template<int AMODE>
__global__ __launch_bounds__(256)
void gemm_one(const void* __restrict__ Ap, GemmArgs g, int M,
              const unsigned short* __restrict__ tb, const float2* __restrict__ pqh,
              unsigned short* __restrict__ hout,
              const unsigned short* __restrict__ WtX, const float* __restrict__ biasX)
{
  __shared__ __align__(16) unsigned char WL[32768];
  unsigned short* Wl = (unsigned short*)WL;
  const int t = threadIdx.x;
  const int m = blockIdx.y;
  const int w = t >> 6, l = t & 63;
  const int lr = l & 15, lkb = (l >> 4) * 8;
  const int r0 = blockIdx.x * 64;
  const bool vrow = (r0 + w * 16 + lr) < M;
  int arow = r0 + w * 16 + lr; if (arow >= M) arow = M - 1;
  const bool wr0 = (m == 0);

  short8v a[4];
  if (AMODE == 2) {
    // chained embedding GEMM: a = bf16(h_in @ WtX + biasX)
#pragma unroll
    for (int p = 0; p < 8; ++p) {
      const int ci = t + p * 256;
      *(short8v*)(WL + swzW(ci >> 4, (ci & 15) * 16)) = *(const short8v*)(WtX + (size_t)ci * 8);
    }
    const float* A = (const float*)Ap;
#pragma unroll
    for (int kk = 0; kk < 4; ++kk) {
      const float* p = A + (size_t)arow * 128 + kk * 32 + lkb;
      const float4 u = *(const float4*)p;
      const float4 v = *(const float4*)(p + 4);
      short8v av;
      av[0]=f2bf(u.x); av[1]=f2bf(u.y); av[2]=f2bf(u.z); av[3]=f2bf(u.w);
      av[4]=f2bf(v.x); av[5]=f2bf(v.y); av[6]=f2bf(v.z); av[7]=f2bf(v.w);
      a[kk] = av;
    }
    __syncthreads();
    f32x4 acc[8];
#pragma unroll
    for (int ct = 0; ct < 8; ++ct) acc[ct] = (f32x4){0.f, 0.f, 0.f, 0.f};
#pragma unroll
    for (int kk = 0; kk < 4; ++kk)
#pragma unroll
      for (int ct = 0; ct < 8; ++ct) {
        const short8v b = *(const short8v*)(WL + swzW(ct * 16 + lr, kk * 64 + (l >> 4) * 16));
        acc[ct] = __builtin_amdgcn_mfma_f32_16x16x32_bf16(a[kk], b, acc[ct], 0, 0, 0);
      }
    __syncthreads();
#pragma unroll
    for (int ct = 0; ct < 8; ++ct) {
      const float bb = biasX[ct * 16 + lr];
#pragma unroll
      for (int q = 0; q < 4; ++q)
        Wl[(w * 16 + (l >> 4) * 4 + q) * 136 + ct * 16 + lr] = f2bf(acc[ct][q] + bb);
    }
    __syncthreads();
#pragma unroll
    for (int kk = 0; kk < 4; ++kk) {
      a[kk] = *(const short8v*)(Wl + (w * 16 + lr) * 136 + kk * 32 + lkb);
      if (wr0 && vrow) *(short8v*)(hout + (size_t)arow * 128 + kk * 32 + lkb) = a[kk];
    }
    __syncthreads();                                 // Wl reads done before restage
  } else if (AMODE == 1) {
    const unsigned short* A = (const unsigned short*)Ap;
#pragma unroll
    for (int kk = 0; kk < 4; ++kk) {
      const short8v tv = *(const short8v*)(tb + (size_t)arow * 128 + kk * 32 + lkb);
      const short8v hr = *(const short8v*)(A + (size_t)arow * 128 + kk * 32 + lkb);
      short8v av;
#pragma unroll
      for (int j = 0; j < 8; ++j) {
        const float2 PQ = pqh[kk * 32 + lkb + j];
        const float x = bf2f((unsigned short)tv[j]) * PQ.x + PQ.y;
        av[j] = (short)f2bf(bf2f((unsigned short)hr[j]) + fmaxf(x, 0.f));
      }
      a[kk] = av;
      if (wr0 && vrow) *(short8v*)(hout + (size_t)arow * 128 + kk * 32 + lkb) = av;
    }
  } else {
    const unsigned short* A = (const unsigned short*)Ap;
#pragma unroll
    for (int kk = 0; kk < 4; ++kk)
      a[kk] = *(const short8v*)(A + (size_t)arow * 128 + kk * 32 + lkb);
  }

  // ---- single GEMM for matrix m ----
#pragma unroll
  for (int p = 0; p < 8; ++p) {
    const int ci = t + p * 256;
    *(short8v*)(WL + swzW(ci >> 4, (ci & 15) * 16)) = *(const short8v*)(g.Wt[m] + (size_t)ci * 8);
  }
  __syncthreads();
  f32x4 acc[8];
#pragma unroll
  for (int ct = 0; ct < 8; ++ct) acc[ct] = (f32x4){0.f, 0.f, 0.f, 0.f};
#pragma unroll
  for (int kk = 0; kk < 4; ++kk)
#pragma unroll
    for (int ct = 0; ct < 8; ++ct) {
      const short8v b = *(const short8v*)(WL + swzW(ct * 16 + lr, kk * 64 + (l >> 4) * 16));
      acc[ct] = __builtin_amdgcn_mfma_f32_16x16x32_bf16(a[kk], b, acc[ct], 0, 0, 0);
    }
  __syncthreads();
#pragma unroll
  for (int ct = 0; ct < 8; ++ct) {
    const float bb = g.bias[m][ct * 16 + lr];
#pragma unroll
    for (int q = 0; q < 4; ++q)
      Wl[(w * 16 + (l >> 4) * 4 + q) * 136 + ct * 16 + lr] = f2bf(acc[ct][q] + bb);
  }
  __syncthreads();
  unsigned short* out = g.out[m];
#pragma unroll
  for (int p = 0; p < 4; ++p) {
    const int ci = t + p * 256;
    const int rr = ci >> 4, co = (ci & 15) * 8;
    const int grow = r0 + rr;
    if (grow < M)
      *(short8v*)(out + (size_t)grow * 128 + co) = *(const short8v*)(Wl + rr * 136 + co);
  }
}

// ============ edge kernel, 64 rows/block; edge tensors in CSR order =========
// LMODE 0: EMB+L0 chain — W and TB both live: 49664 B -> 3 blk/CU
// LMODE 2: MID  — TB overlays SM: exactly 32768 B -> 5 blk/CU
// LMODE 3: LAST — like 2, eres write skipped
// pq read straight from global (L1 broadcast) — no LDS copy.
template<int LMODE>
__global__ __launch_bounds__(256)
void edge_kern(const float* __restrict__ e_in, const int* __restrict__ csr,
               unsigned short* __restrict__ eres, unsigned short* __restrict__ enew,
               const unsigned short* __restrict__ WtEmb, const float* __restrict__ bEmb,
               const unsigned short* __restrict__ WtC, const float* __restrict__ bC,
               const unsigned short* __restrict__ Dh, const unsigned short* __restrict__ Eh,
               const int* __restrict__ csrc, const int* __restrict__ cdst,
               const float* __restrict__ csne, const float2* __restrict__ pq)
{
  extern __shared__ __align__(16) char smem[];
  char* SM = smem;                                          // 32768 B: swizzled W
  unsigned short* TB = (unsigned short*)((LMODE == 0) ? (smem + 32768) : smem);
  const int t = threadIdx.x;
  const int w = t >> 6, l = t & 63;
  const int lr = l & 15, lkb = (l >> 4) * 8;
  const int r0 = blockIdx.x * 64;                           // E % 64 == 0
  const int pos = r0 + w * 16 + lr;

  short8v a[4];
  f32x4 acc[8];

  if (LMODE == 0) {
    // stage Wemb + gather e_in rows (CSR)
#pragma unroll
    for (int p = 0; p < 8; ++p) {
      const int ci = t + p * 256;
      *(short8v*)(SM + swzW(ci >> 4, (ci & 15) * 16)) = *(const short8v*)(WtEmb + (size_t)ci * 8);
    }
#pragma unroll
    for (int p = 0; p < 4; ++p) {
      const int ci = t + p * 256;
      const int rr = ci >> 4, co = (ci & 15) * 8;
      const float* sp = e_in + (size_t)csr[r0 + rr] * 128 + co;
      const float4 u = *(const float4*)sp;
      const float4 v = *(const float4*)(sp + 4);
      short8v av;
      av[0]=f2bf(u.x); av[1]=f2bf(u.y); av[2]=f2bf(u.z); av[3]=f2bf(u.w);
      av[4]=f2bf(v.x); av[5]=f2bf(v.y); av[6]=f2bf(v.z); av[7]=f2bf(v.w);
      *(short8v*)(TB + rr * 132 + co) = av;
    }
    __syncthreads();
#pragma unroll
    for (int kk = 0; kk < 4; ++kk)
      a[kk] = *(const short8v*)(TB + (w * 16 + lr) * 132 + kk * 32 + lkb);
#pragma unroll
    for (int ct = 0; ct < 8; ++ct) acc[ct] = (f32x4){0.f, 0.f, 0.f, 0.f};
#pragma unroll
    for (int kk = 0; kk < 4; ++kk)
#pragma unroll
      for (int ct = 0; ct < 8; ++ct) {
        const short8v b = *(const short8v*)(SM + swzW(ct * 16 + lr, kk * 64 + (l >> 4) * 16));
        acc[ct] = __builtin_amdgcn_mfma_f32_16x16x32_bf16(a[kk], b, acc[ct], 0, 0, 0);
      }
    __syncthreads();
    // transpose emb (+bEmb) -> TB; restage SM with WtC
#pragma unroll
    for (int ct = 0; ct < 8; ++ct) {
      const float bb = bEmb[ct * 16 + lr];
#pragma unroll
      for (int q = 0; q < 4; ++q)
        TB[(w * 16 + (l >> 4) * 4 + q) * 132 + ct * 16 + lr] = f2bf(acc[ct][q] + bb);
    }
#pragma unroll
    for (int p = 0; p < 8; ++p) {
      const int ci = t + p * 256;
      *(short8v*)(SM + swzW(ci >> 4, (ci & 15) * 16)) = *(const short8v*)(WtC + (size_t)ci * 8);
    }
    __syncthreads();
#pragma unroll
    for (int kk = 0; kk < 4; ++kk) {
      a[kk] = *(const short8v*)(TB + (w * 16 + lr) * 132 + kk * 32 + lkb);
      *(short8v*)(eres + (size_t)pos * 128 + kk * 32 + lkb) = a[kk];
    }
  } else {
#pragma unroll
    for (int p = 0; p < 8; ++p) {
      const int ci = t + p * 256;
      *(short8v*)(SM + swzW(ci >> 4, (ci & 15) * 16)) = *(const short8v*)(WtC + (size_t)ci * 8);
    }
    const float sn = csne[pos];
    short8v ep[4], er[4];
#pragma unroll
    for (int kk = 0; kk < 4; ++kk) {
      ep[kk] = *(const short8v*)(enew + (size_t)pos * 128 + kk * 32 + lkb);
      er[kk] = *(const short8v*)(eres + (size_t)pos * 128 + kk * 32 + lkb);
    }
#pragma unroll
    for (int kk = 0; kk < 4; ++kk) {
      short8v av;
#pragma unroll
      for (int j = 0; j < 8; ++j) {
        const float2 PQ = pq[kk * 32 + lkb + j];     // global, L1-broadcast
        const float x = bf2f((unsigned short)ep[kk][j]) * sn * PQ.x + PQ.y;
        av[j] = (short)f2bf(bf2f((unsigned short)er[kk][j]) + fmaxf(x, 0.f));
      }
      a[kk] = av;
      if (LMODE == 2)
        *(short8v*)(eres + (size_t)pos * 128 + kk * 32 + lkb) = av;
    }
    __syncthreads();                                 // W staged
  }

#pragma unroll
  for (int ct = 0; ct < 8; ++ct) acc[ct] = (f32x4){0.f, 0.f, 0.f, 0.f};
#pragma unroll
  for (int kk = 0; kk < 4; ++kk)
#pragma unroll
    for (int ct = 0; ct < 8; ++ct) {
      const short8v b = *(const short8v*)(SM + swzW(ct * 16 + lr, kk * 64 + (l >> 4) * 16));
      acc[ct] = __builtin_amdgcn_mfma_f32_16x16x32_bf16(a[kk], b, acc[ct], 0, 0, 0);
    }
  __syncthreads();                                   // all SM(W)/TB reads done
#pragma unroll
  for (int ct = 0; ct < 8; ++ct) {
    const float bb = bC[ct * 16 + lr];
#pragma unroll
    for (int q = 0; q < 4; ++q)
      TB[(w * 16 + (l >> 4) * 4 + q) * 132 + ct * 16 + lr] = f2bf(acc[ct][q] + bb);
  }
  __syncthreads();
  // epilogue: + Dh[src] + Eh[dst], coalesced short8v stores (CSR order)
#pragma unroll
  for (int p = 0; p < 4; ++p) {
    const int ci = t + p * 256;
    const int rr = ci >> 4, co = (ci & 15) * 8;
    const int pp = r0 + rr;
    const int s = csrc[pp], d = cdst[pp];
    const short8v ce = *(const short8v*)(TB + rr * 132 + co);
    const short8v dv = *(const short8v*)(Dh + (size_t)s * 128 + co);
    const short8v ev = *(const short8v*)(Eh + (size_t)d * 128 + co);
    short8v ov;
#pragma unroll
    for (int j = 0; j < 8; ++j)
      ov[j] = (short)f2bf(bf2f((unsigned short)ce[j]) + bf2f((unsigned short)dv[j]) + bf2f((unsigned short)ev[j]));
    *(short8v*)(enew + (size_t)pp * 128 + co) = ov;
  }
}

// ============ CSR build =====================================================
__global__ void hist_kernel(const int* __restrict__ dst, int* __restrict__ cnt, int E)
{
  const int i = blockIdx.x * 256 + threadIdx.x;
  if (i < E) atomicAdd(&cnt[dst[i]], 1);
}

__global__ void scan_kernel(const int* __restrict__ cnt, int* __restrict__ start,
                            int* __restrict__ cursor, int n, int total)
{
  __shared__ int lds[1024];
  const int tid = threadIdx.x;
  const int chunk = (n + 1023) / 1024;
  const int lo = tid * chunk, hi = min(lo + chunk, n);
  int s = 0;
  for (int i = lo; i < hi; ++i) s += cnt[i];
  lds[tid] = s;
  __syncthreads();
  for (int off = 1; off < 1024; off <<= 1) {
    const int v = (tid >= off) ? lds[tid - off] : 0;
    __syncthreads();
    lds[tid] += v;
    __syncthreads();
  }
  int run = (tid == 0) ? 0 : lds[tid - 1];
  for (int i = lo; i < hi; ++i) { start[i] = run; cursor[i] = run; run += cnt[i]; }
  if (tid == 0) start[n] = total;
}

__global__ void scatter_kernel(const int* __restrict__ dst, const int* __restrict__ src,
                               const float* __restrict__ sne, int* __restrict__ cursor,
                               int* __restrict__ csr, int* __restrict__ csrc,
                               int* __restrict__ cdst, float* __restrict__ csne, int E)
{
  const int i = blockIdx.x * 256 + threadIdx.x;
  if (i < E) {
    const int p = atomicAdd(&cursor[dst[i]], 1);
    csr[p] = i; csrc[p] = src[i]; cdst[p] = dst[i]; csne[p] = sne[i];
  }
}

// ============ aggregate: gated reduce + BN stats ============================
template<int DOE>
__global__ __launch_bounds__(256)
void aggregate(const unsigned short* __restrict__ enew, const unsigned short* __restrict__ Bh,
               const unsigned short* __restrict__ Ah, const float* __restrict__ snorm_n,
               const int* __restrict__ start, const int* __restrict__ csrc,
               const float* __restrict__ csne,
               unsigned short* __restrict__ tbuf, float* __restrict__ statrep)
{
  __shared__ float2 red[16][132];
  const int t = threadIdx.x;
  const int g = t >> 4, q = t & 15;
  const int v = blockIdx.x * 16 + g;             // N % 16 == 0
  const int s0 = start[v], s1 = start[v + 1];
  float num[8] = {0,0,0,0,0,0,0,0}, den[8] = {0,0,0,0,0,0,0,0};
  float psE[8] = {0,0,0,0,0,0,0,0}, pqE[8] = {0,0,0,0,0,0,0,0};

  float sn = 0.f;
  short8v ev = {}, bv = {};
  if (s0 < s1) {
    if (DOE) sn = csne[s0];
    ev = *(const short8v*)(enew + (size_t)s0 * 128 + q * 8);
    bv = *(const short8v*)(Bh + (size_t)csrc[s0] * 128 + q * 8);
  }
  for (int i = s0; i < s1; ++i) {
    float snn = 0.f;
    short8v evn = {}, bvn = {};
    if (i + 1 < s1) {                            // prefetch next edge (seq enew)
      if (DOE) snn = csne[i + 1];
      evn = *(const short8v*)(enew + (size_t)(i + 1) * 128 + q * 8);
      bvn = *(const short8v*)(Bh + (size_t)csrc[i + 1] * 128 + q * 8);
    }
#pragma unroll
    for (int j = 0; j < 8; ++j) {
      const float en = bf2f((unsigned short)ev[j]);
      const float sg = 1.f / (1.f + __expf(-en));
      num[j] = fmaf(sg, bf2f((unsigned short)bv[j]), num[j]);
      den[j] += sg;
      if (DOE) { const float tv = en * sn; psE[j] += tv; pqE[j] = fmaf(tv, tv, pqE[j]); }
    }
    ev = evn; bv = bvn; sn = snn;
  }
  const float snv = snorm_n[v];
  const short8v av = *(const short8v*)(Ah + (size_t)v * 128 + q * 8);
  float hv[8];
  short8v tout;
#pragma unroll
  for (int j = 0; j < 8; ++j) {
    hv[j] = (bf2f((unsigned short)av[j]) + num[j] / (den[j] + 1e-6f)) * snv;
    tout[j] = (short)f2bf(hv[j]);
  }
  *(short8v*)(tbuf + (size_t)v * 128 + q * 8) = tout;

  float* rep = statrep + (size_t)(blockIdx.x & (NREP - 1)) * 512;
#pragma unroll
  for (int j = 0; j < 8; ++j) red[g][q * 8 + j] = make_float2(hv[j], hv[j] * hv[j]);
  __syncthreads();
  if (t < 128) {
    float s = 0.f, qq = 0.f;
    for (int gg = 0; gg < 16; ++gg) { s += red[gg][t].x; qq += red[gg][t].y; }
    atomicAdd(rep + t, s); atomicAdd(rep + 128 + t, qq);
  }
  if (DOE) {
    __syncthreads();
#pragma unroll
    for (int j = 0; j < 8; ++j) red[g][q * 8 + j] = make_float2(psE[j], pqE[j]);
    __syncthreads();
    if (t < 128) {
      float s = 0.f, qq = 0.f;
      for (int gg = 0; gg < 16; ++gg) { s += red[gg][t].x; qq += red[gg][t].y; }
      atomicAdd(rep + 256 + t, s); atomicAdd(rep + 384 + t, qq);
    }
  }
}

// ============ finalize (separate dispatch = cross-block fence) ==============
__global__ void finalize_kernel(float* __restrict__ rep, float2* __restrict__ pqh,
                                float2* __restrict__ pqe,
                                const float* __restrict__ gn_h_l, const float* __restrict__ bt_h_l,
                                const float* __restrict__ gn_e_l, const float* __restrict__ bt_e_l,
                                float invN, float invE, int doE)
{
  const int c = threadIdx.x;
  float sH = 0.f, qH = 0.f, sE = 0.f, qE = 0.f;
  for (int r = 0; r < NREP; ++r) {
    float* p = rep + (size_t)r * 512;
    sH += p[c]; qH += p[128 + c]; sE += p[256 + c]; qE += p[384 + c];
    p[c] = 0.f; p[128 + c] = 0.f; p[256 + c] = 0.f; p[384 + c] = 0.f;
  }
  const float muH = sH * invN;
  const float vH  = fmaxf(qH * invN - muH * muH, 0.f);
  const float PH  = rsqrtf(vH + 1e-5f) * gn_h_l[c];
  pqh[c] = make_float2(PH, bt_h_l[c] - muH * PH);
  if (doE) {
    const float muE = sE * invE;
    const float vE  = fmaxf(qE * invE - muE * muE, 0.f);
    const float PE  = rsqrtf(vE + 1e-5f) * gn_e_l[c];
    pqe[c] = make_float2(PE, bt_e_l[c] - muE * PE);
  }
}

// ============ readout (h-apply of last layer folded in) =====================
__global__ void readout_scatter(const unsigned short* __restrict__ h, const unsigned short* __restrict__ tb,
                                const float2* __restrict__ pqh, const int* __restrict__ gid,
                                float* __restrict__ gsum, int* __restrict__ gcnt, int N)
{
  const int c = threadIdx.x;            // 128
  const float2 PQ = pqh[c];
  const int row0 = blockIdx.x * 256;
  int cur = -1, cnt = 0;
  float s = 0.f;
  for (int r = 0; r < 256; ++r) {
    const int v = row0 + r;
    if (v >= N) break;
    const int g = gid[v];
    if (g != cur) {
      if (cur >= 0) {
        atomicAdd(&gsum[(size_t)cur * 128 + c], s);
        if (c == 0) atomicAdd(&gcnt[cur], cnt);
      }
      cur = g; s = 0.f; cnt = 0;
    }
    s += bf2f(h[(size_t)v * 128 + c]) + fmaxf(bf2f(tb[(size_t)v * 128 + c]) * PQ.x + PQ.y, 0.f);
    ++cnt;
  }
  if (cur >= 0) {
    atomicAdd(&gsum[(size_t)cur * 128 + c], s);
    if (c == 0) atomicAdd(&gcnt[cur], cnt);
  }
}

__global__ void readout_final(const float* __restrict__ gsum, const int* __restrict__ gcnt,
                              const float* __restrict__ Wr, const float* __restrict__ br,
                              float* __restrict__ out)
{
  const int g = blockIdx.x;
  const int t = threadIdx.x;            // 128
  __shared__ float hg[128];
  const float cnt = fmaxf((float)gcnt[g], 1.f);
  hg[t] = gsum[(size_t)g * 128 + t] / cnt;
  __syncthreads();
  if (t < N_CLASS) {
    float acc = br[t];
    for (int k = 0; k < 128; ++k) acc = fmaf(hg[k], Wr[k * N_CLASS + t], acc);
    out[g * N_CLASS + t] = acc;
  }
}

// ============ launcher ======================================================
extern "C" void kernel_launch(void* const* d_in, const int* in_sizes, int n_in,
                              void* d_out, int out_size, void* d_ws, size_t ws_size,
                              hipStream_t stream)
{
  const float* h_in    = (const float*)d_in[0];
  const float* e_in    = (const float*)d_in[1];
  const float* snorm_n = (const float*)d_in[2];
  const float* snorm_e = (const float*)d_in[3];
  const int*   src     = (const int*)d_in[4];
  const int*   dst     = (const int*)d_in[5];
  const int*   gid     = (const int*)d_in[6];
  const float* Wh_emb  = (const float*)d_in[7];
  const float* bh_emb  = (const float*)d_in[8];
  const float* We_emb  = (const float*)d_in[9];
  const float* be_emb  = (const float*)d_in[10];
  const float* WA = (const float*)d_in[11]; const float* bA = (const float*)d_in[12];
  const float* WB = (const float*)d_in[13]; const float* bB = (const float*)d_in[14];
  const float* WC = (const float*)d_in[15]; const float* bC = (const float*)d_in[16];
  const float* WD = (const float*)d_in[17]; const float* bD = (const float*)d_in[18];
  const float* WE = (const float*)d_in[19]; const float* bE = (const float*)d_in[20];
  const float* gn_h = (const float*)d_in[21]; const float* bt_h = (const float*)d_in[22];
  const float* gn_e = (const float*)d_in[23]; const float* bt_e = (const float*)d_in[24];
  const float* Wr = (const float*)d_in[25]; const float* br = (const float*)d_in[26];
  float* out = (float*)d_out;
  (void)in_sizes; (void)n_in; (void)out_size; (void)ws_size;

  char* ws = (char*)d_ws;
  size_t off = 0;
  auto alloc = [&](size_t bytes) -> char* {
    off = (off + 255) & ~(size_t)255;
    char* p = ws + off;
    off += bytes;
    return p;
  };
  const size_t ND = (size_t)N_NODES * 128, ED = (size_t)N_EDGES * 128;
  unsigned short* hbufA = (unsigned short*)alloc(ND * 2);  // ping-pong h
  unsigned short* hbufB = (unsigned short*)alloc(ND * 2);
  unsigned short* ebuf  = (unsigned short*)alloc(ED * 2);  // residual e (CSR order)
  unsigned short* enew  = (unsigned short*)alloc(ED * 2);  // pre-BN e_new (CSR order)
  unsigned short* Ah   = (unsigned short*)alloc(ND * 2);
  unsigned short* Bh   = (unsigned short*)alloc(ND * 2);
  unsigned short* Dh   = (unsigned short*)alloc(ND * 2);
  unsigned short* Eh   = (unsigned short*)alloc(ND * 2);
  unsigned short* tbuf = (unsigned short*)alloc(ND * 2);   // pre-BN h_new (bf16)
  unsigned short* Wt   = (unsigned short*)alloc((size_t)17 * 16384 * 2);
  float2* pqh          = (float2*)alloc(128 * 8);
  float2* pqe          = (float2*)alloc(128 * 8);
  int* start  = (int*)alloc((size_t)(N_NODES + 1) * 4);
  int* cursor = (int*)alloc((size_t)N_NODES * 4);
  int* csr    = (int*)alloc((size_t)N_EDGES * 4);
  int* csrc   = (int*)alloc((size_t)N_EDGES * 4);
  int* cdst   = (int*)alloc((size_t)N_EDGES * 4);
  float* csne = (float*)alloc((size_t)N_EDGES * 4);
  // ---- contiguous zero-region (single memset) ----
  char* zbase = (char*)alloc(0);
  int*   cnt     = (int*)alloc((size_t)N_NODES * 4);
  float* statrep = (float*)alloc((size_t)NREP * 512 * 4);
  float* gsum    = (float*)alloc((size_t)N_GRAPHS * 128 * 4);
  int*   gcnt    = (int*)alloc((size_t)N_GRAPHS * 4);
  char* zend = (char*)alloc(0);

  hipMemsetAsync(zbase, 0, (size_t)(zend - zbase), stream);

  wconv<<<17 * 64, 256, 0, stream>>>(Wh_emb, We_emb, WA, WB, WC, WD, WE, Wt);

  hist_kernel<<<(N_EDGES + 255) / 256, 256, 0, stream>>>(dst, cnt, N_EDGES);
  scan_kernel<<<1, 1024, 0, stream>>>(cnt, start, cursor, N_NODES, N_EDGES);
  scatter_kernel<<<(N_EDGES + 255) / 256, 256, 0, stream>>>(dst, src, snorm_e, cursor,
                                                            csr, csrc, cdst, csne, N_EDGES);

  const int gbN = (N_NODES + 63) / 64;   // 469
  const int gbE = N_EDGES / 64;          // 7500
  const dim3 gN(gbN, 4);
  const unsigned SH0 = 49664;            // LMODE 0: W + TB
  const unsigned SH2 = 32768;            // LMODE 2/3: W/TB overlay -> 5 blk/CU

  unsigned short* hcur = hbufA;          // h_l input buffer
  unsigned short* hnxt = hbufB;

  for (int l = 0; l < N_LAYERS; ++l) {
    const size_t bOff = (size_t)l * 128;
    const int doE = (l < N_LAYERS - 1) ? 1 : 0;
    // node GEMMs: one matrix per block (blockIdx.y), ping-pong h buffers
    {
      GemmArgs g{};
      g.Wt[0] = Wt + (size_t)(2 + l)  * 16384; g.bias[0] = bA + bOff; g.out[0] = Ah;
      g.Wt[1] = Wt + (size_t)(5 + l)  * 16384; g.bias[1] = bB + bOff; g.out[1] = Bh;
      g.Wt[2] = Wt + (size_t)(11 + l) * 16384; g.bias[2] = bD + bOff; g.out[2] = Dh;
      g.Wt[3] = Wt + (size_t)(14 + l) * 16384; g.bias[3] = bE + bOff; g.out[3] = Eh;
      if (l == 0) {
        // reads h_in (const), y==0 writes h0 -> hcur
        gemm_one<2><<<gN, 256, 0, stream>>>(h_in, g, N_NODES, nullptr, nullptr, hcur,
                                            Wt + 0 * 16384, bh_emb);
      } else {
        // reads hcur (const here), y==0 writes h_l -> hnxt; then swap
        gemm_one<1><<<gN, 256, 0, stream>>>(hcur, g, N_NODES, tbuf, pqh, hnxt,
                                            nullptr, nullptr);
        unsigned short* tmp = hcur; hcur = hnxt; hnxt = tmp;
      }
    }
    // edge kernel (CSR order; e BN-apply of prev layer folded into A-load)
    const unsigned short* WtC = Wt + (size_t)(8 + l) * 16384;
    if (l == 0)
      edge_kern<0><<<gbE, 256, SH0, stream>>>(e_in, csr, ebuf, enew, Wt + 1 * 16384, be_emb,
                                              WtC, bC + bOff, Dh, Eh, csrc, cdst, csne, nullptr);
    else if (l == 1)
      edge_kern<2><<<gbE, 256, SH2, stream>>>(nullptr, nullptr, ebuf, enew, nullptr, nullptr,
                                              WtC, bC + bOff, Dh, Eh, csrc, cdst, csne, pqe);
    else
      edge_kern<3><<<gbE, 256, SH2, stream>>>(nullptr, nullptr, ebuf, enew, nullptr, nullptr,
                                              WtC, bC + bOff, Dh, Eh, csrc, cdst, csne, pqe);
    // gated reduce + BN stats (streaming enew), then tiny finalize dispatch
    if (doE)
      aggregate<1><<<N_NODES / 16, 256, 0, stream>>>(enew, Bh, Ah, snorm_n, start, csrc, csne,
                                                     tbuf, statrep);
    else
      aggregate<0><<<N_NODES / 16, 256, 0, stream>>>(enew, Bh, Ah, snorm_n, start, csrc, csne,
                                                     tbuf, statrep);
    finalize_kernel<<<1, 128, 0, stream>>>(statrep, pqh, pqe, gn_h + bOff, bt_h + bOff,
                                           gn_e + bOff, bt_e + bOff,
                                           1.f / N_NODES, 1.f / N_EDGES, doE);
  }

  // readout (final h-apply folded); hcur holds h2 after the loop
  readout_scatter<<<(N_NODES + 255) / 256, 128, 0, stream>>>(hcur, tbuf, pqh, gid, gsum, gcnt, N_NODES);
  readout_final<<<N_GRAPHS, 128, 0, stream>>>(gsum, gcnt, Wr, br, out);
}

// Round 11
// 904.941 us; speedup vs baseline: 1.0399x; 1.0399x over previous
//
#include <hip/hip_runtime.h>
#include <cstdint>
#include <cstddef>

#define N_NODES  30000
#define N_EDGES  480000
#define N_LAYERS 3
#define N_GRAPHS 64
#define N_CLASS  10
#define NREP     32

typedef __attribute__((ext_vector_type(8))) short short8v;   // 8 bf16 (4 VGPR)
typedef __attribute__((ext_vector_type(4))) float f32x4;

__device__ __forceinline__ unsigned short f2bf(float x) {
  union { float f; unsigned u; } v; v.f = x;
  unsigned r = v.u + 0x7FFFu + ((v.u >> 16) & 1u);   // RNE
  return (unsigned short)(r >> 16);
}
__device__ __forceinline__ float bf2f(unsigned short h) {
  union { unsigned u; float f; } v; v.u = ((unsigned)h) << 16;
  return v.f;
}
// XOR-swizzle for the [128 rows x 256B] W tile (guide §6 G4).
__device__ __forceinline__ int swzW(int row, int off16) {
  return (row << 8) | (off16 ^ ((row & 7) << 4));
}

// ============ weight convert + transpose: Wt[mi][n][k] = bf16(W[k][n]) ======
__global__ void wconv(const float* __restrict__ Wh, const float* __restrict__ We,
                      const float* __restrict__ WA, const float* __restrict__ WB,
                      const float* __restrict__ WC, const float* __restrict__ WD,
                      const float* __restrict__ WE, unsigned short* __restrict__ Wt)
{
  const int mi  = blockIdx.x >> 6;
  const int idx = (blockIdx.x & 63) * 256 + threadIdx.x;   // 0..16383
  const float* src;
  if      (mi == 0) src = Wh;
  else if (mi == 1) src = We;
  else if (mi < 5)  src = WA + (size_t)(mi - 2) * 16384;
  else if (mi < 8)  src = WB + (size_t)(mi - 5) * 16384;
  else if (mi < 11) src = WC + (size_t)(mi - 8) * 16384;
  else if (mi < 14) src = WD + (size_t)(mi - 11) * 16384;
  else              src = WE + (size_t)(mi - 14) * 16384;
  const int k = idx >> 7, n = idx & 127;
  Wt[(size_t)mi * 16384 + (size_t)n * 128 + k] = f2bf(src[idx]);
}

// ============ node GEMM: out_m = A @ W_m + b_m (NMAT outputs share A) =======
// AMODE 0: plain bf16 A; 1: BN-fold (A = hbuf + relu(tbuf*P+Q), write back);
// AMODE 2: emb chain (A = bf16(h_in_fp32 @ WtX + biasX), write hbuf)
struct GemmArgs {
  const unsigned short* Wt[4];
  const float* bias[4];
  unsigned short* out[4];
};

template<int NMAT, int AMODE>
__global__ __launch_bounds__(256)
void gemm_mm(const void* __restrict__ Ap, GemmArgs g, int M,
             const unsigned short* __restrict__ tb, const float2* __restrict__ pqh,
             unsigned short* __restrict__ hout,
             const unsigned short* __restrict__ WtX, const float* __restrict__ biasX)
{
  __shared__ __align__(16) unsigned char WL[32768];
  unsigned short* Wl = (unsigned short*)WL;
  const int t = threadIdx.x;
  const int w = t >> 6, l = t & 63;
  const int lr = l & 15, lkb = (l >> 4) * 8;
  const int r0 = blockIdx.x * 64;
  const bool vrow = (r0 + w * 16 + lr) < M;
  int arow = r0 + w * 16 + lr; if (arow >= M) arow = M - 1;

  short8v a[4];
  if (AMODE == 2) {
#pragma unroll
    for (int p = 0; p < 8; ++p) {
      const int ci = t + p * 256;
      *(short8v*)(WL + swzW(ci >> 4, (ci & 15) * 16)) = *(const short8v*)(WtX + (size_t)ci * 8);
    }
    const float* A = (const float*)Ap;
#pragma unroll
    for (int kk = 0; kk < 4; ++kk) {
      const float* p = A + (size_t)arow * 128 + kk * 32 + lkb;
      const float4 u = *(const float4*)p;
      const float4 v = *(const float4*)(p + 4);
      short8v av;
      av[0]=f2bf(u.x); av[1]=f2bf(u.y); av[2]=f2bf(u.z); av[3]=f2bf(u.w);
      av[4]=f2bf(v.x); av[5]=f2bf(v.y); av[6]=f2bf(v.z); av[7]=f2bf(v.w);
      a[kk] = av;
    }
    __syncthreads();
    f32x4 acc[8];
#pragma unroll
    for (int ct = 0; ct < 8; ++ct) acc[ct] = (f32x4){0.f, 0.f, 0.f, 0.f};
#pragma unroll
    for (int kk = 0; kk < 4; ++kk)
#pragma unroll
      for (int ct = 0; ct < 8; ++ct) {
        const short8v b = *(const short8v*)(WL + swzW(ct * 16 + lr, kk * 64 + (l >> 4) * 16));
        acc[ct] = __builtin_amdgcn_mfma_f32_16x16x32_bf16(a[kk], b, acc[ct], 0, 0, 0);
      }
    __syncthreads();
#pragma unroll
    for (int ct = 0; ct < 8; ++ct) {
      const float bb = biasX[ct * 16 + lr];
#pragma unroll
      for (int q = 0; q < 4; ++q)
        Wl[(w * 16 + (l >> 4) * 4 + q) * 136 + ct * 16 + lr] = f2bf(acc[ct][q] + bb);
    }
    __syncthreads();
#pragma unroll
    for (int kk = 0; kk < 4; ++kk) {
      a[kk] = *(const short8v*)(Wl + (w * 16 + lr) * 136 + kk * 32 + lkb);
      if (vrow) *(short8v*)(hout + (size_t)arow * 128 + kk * 32 + lkb) = a[kk];
    }
  } else if (AMODE == 1) {
    const unsigned short* A = (const unsigned short*)Ap;
#pragma unroll
    for (int kk = 0; kk < 4; ++kk) {
      const short8v tv = *(const short8v*)(tb + (size_t)arow * 128 + kk * 32 + lkb);
      const short8v hr = *(const short8v*)(A + (size_t)arow * 128 + kk * 32 + lkb);
      short8v av;
#pragma unroll
      for (int j = 0; j < 8; ++j) {
        const float2 PQ = pqh[kk * 32 + lkb + j];
        const float x = bf2f((unsigned short)tv[j]) * PQ.x + PQ.y;
        av[j] = (short)f2bf(bf2f((unsigned short)hr[j]) + fmaxf(x, 0.f));
      }
      a[kk] = av;
      if (vrow) *(short8v*)(hout + (size_t)arow * 128 + kk * 32 + lkb) = av;
    }
  } else {
    const unsigned short* A = (const unsigned short*)Ap;
#pragma unroll
    for (int kk = 0; kk < 4; ++kk)
      a[kk] = *(const short8v*)(A + (size_t)arow * 128 + kk * 32 + lkb);
  }

#pragma unroll
  for (int m = 0; m < NMAT; ++m) {
    if (m || AMODE == 2) __syncthreads();
#pragma unroll
    for (int p = 0; p < 8; ++p) {
      const int ci = t + p * 256;
      *(short8v*)(WL + swzW(ci >> 4, (ci & 15) * 16)) = *(const short8v*)(g.Wt[m] + (size_t)ci * 8);
    }
    __syncthreads();
    f32x4 acc[8];
#pragma unroll
    for (int ct = 0; ct < 8; ++ct) acc[ct] = (f32x4){0.f, 0.f, 0.f, 0.f};
#pragma unroll
    for (int kk = 0; kk < 4; ++kk)
#pragma unroll
      for (int ct = 0; ct < 8; ++ct) {
        const short8v b = *(const short8v*)(WL + swzW(ct * 16 + lr, kk * 64 + (l >> 4) * 16));
        acc[ct] = __builtin_amdgcn_mfma_f32_16x16x32_bf16(a[kk], b, acc[ct], 0, 0, 0);
      }
    __syncthreads();
#pragma unroll
    for (int ct = 0; ct < 8; ++ct) {
      const float bb = g.bias[m][ct * 16 + lr];
#pragma unroll
      for (int q = 0; q < 4; ++q)
        Wl[(w * 16 + (l >> 4) * 4 + q) * 136 + ct * 16 + lr] = f2bf(acc[ct][q] + bb);
    }
    __syncthreads();
    unsigned short* out = g.out[m];
#pragma unroll
    for (int p = 0; p < 4; ++p) {
      const int ci = t + p * 256;
      const int rr = ci >> 4, co = (ci & 15) * 8;
      const int grow = r0 + rr;
      if (grow < M)
        *(short8v*)(out + (size_t)grow * 128 + co) = *(const short8v*)(Wl + rr * 136 + co);
    }
  }
}

// ============ edge kernel, 64 rows/block; edge tensors in CSR order =========
// LMODE 0: EMB+L0 chain (W + TB both live: 49664 B)
// LMODE 2: MID  — TB overlays SM (32768 B)
// LMODE 3: LAST — like 2, eres write skipped
// Dh/Eh epilogue gathers are ISSUED before the MFMA loop (addresses known at
// entry) so their ~300-900cy latency hides under the GEMM (T14 adapted:
// barrier drains vmcnt, so issue point = just after the last pre-GEMM sync).
template<int LMODE>
__global__ __launch_bounds__(256)
void edge_kern(const float* __restrict__ e_in, const int* __restrict__ csr,
               unsigned short* __restrict__ eres, unsigned short* __restrict__ enew,
               const unsigned short* __restrict__ WtEmb, const float* __restrict__ bEmb,
               const unsigned short* __restrict__ WtC, const float* __restrict__ bC,
               const unsigned short* __restrict__ Dh, const unsigned short* __restrict__ Eh,
               const int* __restrict__ csrc, const int* __restrict__ cdst,
               const float* __restrict__ csne, const float2* __restrict__ pq)
{
  extern __shared__ __align__(16) char smem[];
  char* SM = smem;                                          // 32768 B: swizzled W
  unsigned short* TB = (unsigned short*)((LMODE == 0) ? (smem + 32768) : smem);
  const int t = threadIdx.x;
  const int w = t >> 6, l = t & 63;
  const int lr = l & 15, lkb = (l >> 4) * 8;
  const int r0 = blockIdx.x * 64;                           // E % 64 == 0
  const int pos = r0 + w * 16 + lr;

  short8v a[4];
  f32x4 acc[8];
  short8v dpre[4], epre[4];                                 // prefetched gathers

  if (LMODE == 0) {
    // stage Wemb + gather e_in rows (CSR)
#pragma unroll
    for (int p = 0; p < 8; ++p) {
      const int ci = t + p * 256;
      *(short8v*)(SM + swzW(ci >> 4, (ci & 15) * 16)) = *(const short8v*)(WtEmb + (size_t)ci * 8);
    }
#pragma unroll
    for (int p = 0; p < 4; ++p) {
      const int ci = t + p * 256;
      const int rr = ci >> 4, co = (ci & 15) * 8;
      const float* sp = e_in + (size_t)csr[r0 + rr] * 128 + co;
      const float4 u = *(const float4*)sp;
      const float4 v = *(const float4*)(sp + 4);
      short8v av;
      av[0]=f2bf(u.x); av[1]=f2bf(u.y); av[2]=f2bf(u.z); av[3]=f2bf(u.w);
      av[4]=f2bf(v.x); av[5]=f2bf(v.y); av[6]=f2bf(v.z); av[7]=f2bf(v.w);
      *(short8v*)(TB + rr * 132 + co) = av;
    }
    __syncthreads();
#pragma unroll
    for (int kk = 0; kk < 4; ++kk)
      a[kk] = *(const short8v*)(TB + (w * 16 + lr) * 132 + kk * 32 + lkb);
#pragma unroll
    for (int ct = 0; ct < 8; ++ct) acc[ct] = (f32x4){0.f, 0.f, 0.f, 0.f};
#pragma unroll
    for (int kk = 0; kk < 4; ++kk)
#pragma unroll
      for (int ct = 0; ct < 8; ++ct) {
        const short8v b = *(const short8v*)(SM + swzW(ct * 16 + lr, kk * 64 + (l >> 4) * 16));
        acc[ct] = __builtin_amdgcn_mfma_f32_16x16x32_bf16(a[kk], b, acc[ct], 0, 0, 0);
      }
    __syncthreads();
    // transpose emb (+bEmb) -> TB; restage SM with WtC
#pragma unroll
    for (int ct = 0; ct < 8; ++ct) {
      const float bb = bEmb[ct * 16 + lr];
#pragma unroll
      for (int q = 0; q < 4; ++q)
        TB[(w * 16 + (l >> 4) * 4 + q) * 132 + ct * 16 + lr] = f2bf(acc[ct][q] + bb);
    }
#pragma unroll
    for (int p = 0; p < 8; ++p) {
      const int ci = t + p * 256;
      *(short8v*)(SM + swzW(ci >> 4, (ci & 15) * 16)) = *(const short8v*)(WtC + (size_t)ci * 8);
    }
    __syncthreads();
#pragma unroll
    for (int kk = 0; kk < 4; ++kk) {
      a[kk] = *(const short8v*)(TB + (w * 16 + lr) * 132 + kk * 32 + lkb);
      *(short8v*)(eres + (size_t)pos * 128 + kk * 32 + lkb) = a[kk];
    }
  } else {
#pragma unroll
    for (int p = 0; p < 8; ++p) {
      const int ci = t + p * 256;
      *(short8v*)(SM + swzW(ci >> 4, (ci & 15) * 16)) = *(const short8v*)(WtC + (size_t)ci * 8);
    }
    const float sn = csne[pos];
    short8v ep[4], er[4];
#pragma unroll
    for (int kk = 0; kk < 4; ++kk) {
      ep[kk] = *(const short8v*)(enew + (size_t)pos * 128 + kk * 32 + lkb);
      er[kk] = *(const short8v*)(eres + (size_t)pos * 128 + kk * 32 + lkb);
    }
#pragma unroll
    for (int kk = 0; kk < 4; ++kk) {
      short8v av;
#pragma unroll
      for (int j = 0; j < 8; ++j) {
        const float2 PQ = pq[kk * 32 + lkb + j];     // global, L1-broadcast
        const float x = bf2f((unsigned short)ep[kk][j]) * sn * PQ.x + PQ.y;
        av[j] = (short)f2bf(bf2f((unsigned short)er[kk][j]) + fmaxf(x, 0.f));
      }
      a[kk] = av;
      if (LMODE == 2)
        *(short8v*)(eres + (size_t)pos * 128 + kk * 32 + lkb) = av;
    }
    __syncthreads();                                 // W staged
  }

  // ---- issue epilogue gathers NOW; latency hides under the MFMA loop ----
#pragma unroll
  for (int p = 0; p < 4; ++p) {
    const int ci = t + p * 256;
    const int rr = ci >> 4, co = (ci & 15) * 8;
    const int pp = r0 + rr;
    dpre[p] = *(const short8v*)(Dh + (size_t)csrc[pp] * 128 + co);
    epre[p] = *(const short8v*)(Eh + (size_t)cdst[pp] * 128 + co);
  }

#pragma unroll
  for (int ct = 0; ct < 8; ++ct) acc[ct] = (f32x4){0.f, 0.f, 0.f, 0.f};
#pragma unroll
  for (int kk = 0; kk < 4; ++kk)
#pragma unroll
    for (int ct = 0; ct < 8; ++ct) {
      const short8v b = *(const short8v*)(SM + swzW(ct * 16 + lr, kk * 64 + (l >> 4) * 16));
      acc[ct] = __builtin_amdgcn_mfma_f32_16x16x32_bf16(a[kk], b, acc[ct], 0, 0, 0);
    }
  __syncthreads();                                   // all SM(W)/TB reads done
#pragma unroll
  for (int ct = 0; ct < 8; ++ct) {
    const float bb = bC[ct * 16 + lr];
#pragma unroll
    for (int q = 0; q < 4; ++q)
      TB[(w * 16 + (l >> 4) * 4 + q) * 132 + ct * 16 + lr] = f2bf(acc[ct][q] + bb);
  }
  __syncthreads();
  // epilogue: Ce + prefetched Dh/Eh, coalesced short8v stores (CSR order)
#pragma unroll
  for (int p = 0; p < 4; ++p) {
    const int ci = t + p * 256;
    const int rr = ci >> 4, co = (ci & 15) * 8;
    const int pp = r0 + rr;
    const short8v ce = *(const short8v*)(TB + rr * 132 + co);
    short8v ov;
#pragma unroll
    for (int j = 0; j < 8; ++j)
      ov[j] = (short)f2bf(bf2f((unsigned short)ce[j]) + bf2f((unsigned short)dpre[p][j]) + bf2f((unsigned short)epre[p][j]));
    *(short8v*)(enew + (size_t)pp * 128 + co) = ov;
  }
}

// ============ CSR build =====================================================
__global__ void hist_kernel(const int* __restrict__ dst, int* __restrict__ cnt, int E)
{
  const int i = blockIdx.x * 256 + threadIdx.x;
  if (i < E) atomicAdd(&cnt[dst[i]], 1);
}

__global__ void scan_kernel(const int* __restrict__ cnt, int* __restrict__ start,
                            int* __restrict__ cursor, int n, int total)
{
  __shared__ int lds[1024];
  const int tid = threadIdx.x;
  const int chunk = (n + 1023) / 1024;
  const int lo = tid * chunk, hi = min(lo + chunk, n);
  int s = 0;
  for (int i = lo; i < hi; ++i) s += cnt[i];
  lds[tid] = s;
  __syncthreads();
  for (int off = 1; off < 1024; off <<= 1) {
    const int v = (tid >= off) ? lds[tid - off] : 0;
    __syncthreads();
    lds[tid] += v;
    __syncthreads();
  }
  int run = (tid == 0) ? 0 : lds[tid - 1];
  for (int i = lo; i < hi; ++i) { start[i] = run; cursor[i] = run; run += cnt[i]; }
  if (tid == 0) start[n] = total;
}

__global__ void scatter_kernel(const int* __restrict__ dst, const int* __restrict__ src,
                               const float* __restrict__ sne, int* __restrict__ cursor,
                               int* __restrict__ csr, int* __restrict__ csrc,
                               int* __restrict__ cdst, float* __restrict__ csne, int E)
{
  const int i = blockIdx.x * 256 + threadIdx.x;
  if (i < E) {
    const int p = atomicAdd(&cursor[dst[i]], 1);
    csr[p] = i; csrc[p] = src[i]; cdst[p] = dst[i]; csne[p] = sne[i];
  }
}

// ============ aggregate: gated reduce + BN stats ============================
template<int DOE>
__global__ __launch_bounds__(256)
void aggregate(const unsigned short* __restrict__ enew, const unsigned short* __restrict__ Bh,
               const unsigned short* __restrict__ Ah, const float* __restrict__ snorm_n,
               const int* __restrict__ start, const int* __restrict__ csrc,
               const float* __restrict__ csne,
               unsigned short* __restrict__ tbuf, float* __restrict__ statrep)
{
  __shared__ float2 red[16][132];
  const int t = threadIdx.x;
  const int g = t >> 4, q = t & 15;
  const int v = blockIdx.x * 16 + g;             // N % 16 == 0
  const int s0 = start[v], s1 = start[v + 1];
  float num[8] = {0,0,0,0,0,0,0,0}, den[8] = {0,0,0,0,0,0,0,0};
  float psE[8] = {0,0,0,0,0,0,0,0}, pqE[8] = {0,0,0,0,0,0,0,0};

  float sn = 0.f;
  short8v ev = {}, bv = {};
  if (s0 < s1) {
    if (DOE) sn = csne[s0];
    ev = *(const short8v*)(enew + (size_t)s0 * 128 + q * 8);
    bv = *(const short8v*)(Bh + (size_t)csrc[s0] * 128 + q * 8);
  }
  for (int i = s0; i < s1; ++i) {
    float snn = 0.f;
    short8v evn = {}, bvn = {};
    if (i + 1 < s1) {                            // prefetch next edge (seq enew)
      if (DOE) snn = csne[i + 1];
      evn = *(const short8v*)(enew + (size_t)(i + 1) * 128 + q * 8);
      bvn = *(const short8v*)(Bh + (size_t)csrc[i + 1] * 128 + q * 8);
    }
#pragma unroll
    for (int j = 0; j < 8; ++j) {
      const float en = bf2f((unsigned short)ev[j]);
      const float sg = 1.f / (1.f + __expf(-en));
      num[j] = fmaf(sg, bf2f((unsigned short)bv[j]), num[j]);
      den[j] += sg;
      if (DOE) { const float tv = en * sn; psE[j] += tv; pqE[j] = fmaf(tv, tv, pqE[j]); }
    }
    ev = evn; bv = bvn; sn = snn;
  }
  const float snv = snorm_n[v];
  const short8v av = *(const short8v*)(Ah + (size_t)v * 128 + q * 8);
  float hv[8];
  short8v tout;
#pragma unroll
  for (int j = 0; j < 8; ++j) {
    hv[j] = (bf2f((unsigned short)av[j]) + num[j] / (den[j] + 1e-6f)) * snv;
    tout[j] = (short)f2bf(hv[j]);
  }
  *(short8v*)(tbuf + (size_t)v * 128 + q * 8) = tout;

  float* rep = statrep + (size_t)(blockIdx.x & (NREP - 1)) * 512;
#pragma unroll
  for (int j = 0; j < 8; ++j) red[g][q * 8 + j] = make_float2(hv[j], hv[j] * hv[j]);
  __syncthreads();
  if (t < 128) {
    float s = 0.f, qq = 0.f;
    for (int gg = 0; gg < 16; ++gg) { s += red[gg][t].x; qq += red[gg][t].y; }
    atomicAdd(rep + t, s); atomicAdd(rep + 128 + t, qq);
  }
  if (DOE) {
    __syncthreads();
#pragma unroll
    for (int j = 0; j < 8; ++j) red[g][q * 8 + j] = make_float2(psE[j], pqE[j]);
    __syncthreads();
    if (t < 128) {
      float s = 0.f, qq = 0.f;
      for (int gg = 0; gg < 16; ++gg) { s += red[gg][t].x; qq += red[gg][t].y; }
      atomicAdd(rep + 256 + t, s); atomicAdd(rep + 384 + t, qq);
    }
  }
}

// ============ finalize (separate dispatch = cross-block fence) ==============
__global__ void finalize_kernel(float* __restrict__ rep, float2* __restrict__ pqh,
                                float2* __restrict__ pqe,
                                const float* __restrict__ gn_h_l, const float* __restrict__ bt_h_l,
                                const float* __restrict__ gn_e_l, const float* __restrict__ bt_e_l,
                                float invN, float invE, int doE)
{
  const int c = threadIdx.x;
  float sH = 0.f, qH = 0.f, sE = 0.f, qE = 0.f;
  for (int r = 0; r < NREP; ++r) {
    float* p = rep + (size_t)r * 512;
    sH += p[c]; qH += p[128 + c]; sE += p[256 + c]; qE += p[384 + c];
    p[c] = 0.f; p[128 + c] = 0.f; p[256 + c] = 0.f; p[384 + c] = 0.f;
  }
  const float muH = sH * invN;
  const float vH  = fmaxf(qH * invN - muH * muH, 0.f);
  const float PH  = rsqrtf(vH + 1e-5f) * gn_h_l[c];
  pqh[c] = make_float2(PH, bt_h_l[c] - muH * PH);
  if (doE) {
    const float muE = sE * invE;
    const float vE  = fmaxf(qE * invE - muE * muE, 0.f);
    const float PE  = rsqrtf(vE + 1e-5f) * gn_e_l[c];
    pqe[c] = make_float2(PE, bt_e_l[c] - muE * PE);
  }
}

// ============ readout (h-apply of last layer folded in) =====================
__global__ void readout_scatter(const unsigned short* __restrict__ h, const unsigned short* __restrict__ tb,
                                const float2* __restrict__ pqh, const int* __restrict__ gid,
                                float* __restrict__ gsum, int* __restrict__ gcnt, int N)
{
  const int c = threadIdx.x;            // 128
  const float2 PQ = pqh[c];
  const int row0 = blockIdx.x * 256;
  int cur = -1, cnt = 0;
  float s = 0.f;
  for (int r = 0; r < 256; ++r) {
    const int v = row0 + r;
    if (v >= N) break;
    const int g = gid[v];
    if (g != cur) {
      if (cur >= 0) {
        atomicAdd(&gsum[(size_t)cur * 128 + c], s);
        if (c == 0) atomicAdd(&gcnt[cur], cnt);
      }
      cur = g; s = 0.f; cnt = 0;
    }
    s += bf2f(h[(size_t)v * 128 + c]) + fmaxf(bf2f(tb[(size_t)v * 128 + c]) * PQ.x + PQ.y, 0.f);
    ++cnt;
  }
  if (cur >= 0) {
    atomicAdd(&gsum[(size_t)cur * 128 + c], s);
    if (c == 0) atomicAdd(&gcnt[cur], cnt);
  }
}

__global__ void readout_final(const float* __restrict__ gsum, const int* __restrict__ gcnt,
                              const float* __restrict__ Wr, const float* __restrict__ br,
                              float* __restrict__ out)
{
  const int g = blockIdx.x;
  const int t = threadIdx.x;            // 128
  __shared__ float hg[128];
  const float cnt = fmaxf((float)gcnt[g], 1.f);
  hg[t] = gsum[(size_t)g * 128 + t] / cnt;
  __syncthreads();
  if (t < N_CLASS) {
    float acc = br[t];
    for (int k = 0; k < 128; ++k) acc = fmaf(hg[k], Wr[k * N_CLASS + t], acc);
    out[g * N_CLASS + t] = acc;
  }
}

// ============ launcher ======================================================
extern "C" void kernel_launch(void* const* d_in, const int* in_sizes, int n_in,
                              void* d_out, int out_size, void* d_ws, size_t ws_size,
                              hipStream_t stream)
{
  const float* h_in    = (const float*)d_in[0];
  const float* e_in    = (const float*)d_in[1];
  const float* snorm_n = (const float*)d_in[2];
  const float* snorm_e = (const float*)d_in[3];
  const int*   src     = (const int*)d_in[4];
  const int*   dst     = (const int*)d_in[5];
  const int*   gid     = (const int*)d_in[6];
  const float* Wh_emb  = (const float*)d_in[7];
  const float* bh_emb  = (const float*)d_in[8];
  const float* We_emb  = (const float*)d_in[9];
  const float* be_emb  = (const float*)d_in[10];
  const float* WA = (const float*)d_in[11]; const float* bA = (const float*)d_in[12];
  const float* WB = (const float*)d_in[13]; const float* bB = (const float*)d_in[14];
  const float* WC = (const float*)d_in[15]; const float* bC = (const float*)d_in[16];
  const float* WD = (const float*)d_in[17]; const float* bD = (const float*)d_in[18];
  const float* WE = (const float*)d_in[19]; const float* bE = (const float*)d_in[20];
  const float* gn_h = (const float*)d_in[21]; const float* bt_h = (const float*)d_in[22];
  const float* gn_e = (const float*)d_in[23]; const float* bt_e = (const float*)d_in[24];
  const float* Wr = (const float*)d_in[25]; const float* br = (const float*)d_in[26];
  float* out = (float*)d_out;
  (void)in_sizes; (void)n_in; (void)out_size; (void)ws_size;

  char* ws = (char*)d_ws;
  size_t off = 0;
  auto alloc = [&](size_t bytes) -> char* {
    off = (off + 255) & ~(size_t)255;
    char* p = ws + off;
    off += bytes;
    return p;
  };
  const size_t ND = (size_t)N_NODES * 128, ED = (size_t)N_EDGES * 128;
  unsigned short* hbuf = (unsigned short*)alloc(ND * 2);
  unsigned short* ebuf = (unsigned short*)alloc(ED * 2);   // residual e (CSR order)
  unsigned short* enew = (unsigned short*)alloc(ED * 2);   // pre-BN e_new (CSR order)
  unsigned short* Ah   = (unsigned short*)alloc(ND * 2);
  unsigned short* Bh   = (unsigned short*)alloc(ND * 2);
  unsigned short* Dh   = (unsigned short*)alloc(ND * 2);
  unsigned short* Eh   = (unsigned short*)alloc(ND * 2);
  unsigned short* tbuf = (unsigned short*)alloc(ND * 2);   // pre-BN h_new (bf16)
  unsigned short* Wt   = (unsigned short*)alloc((size_t)17 * 16384 * 2);
  float2* pqh          = (float2*)alloc(128 * 8);
  float2* pqe          = (float2*)alloc(128 * 8);
  int* start  = (int*)alloc((size_t)(N_NODES + 1) * 4);
  int* cursor = (int*)alloc((size_t)N_NODES * 4);
  int* csr    = (int*)alloc((size_t)N_EDGES * 4);
  int* csrc   = (int*)alloc((size_t)N_EDGES * 4);
  int* cdst   = (int*)alloc((size_t)N_EDGES * 4);
  float* csne = (float*)alloc((size_t)N_EDGES * 4);
  // ---- contiguous zero-region (single memset) ----
  char* zbase = (char*)alloc(0);
  int*   cnt     = (int*)alloc((size_t)N_NODES * 4);
  float* statrep = (float*)alloc((size_t)NREP * 512 * 4);
  float* gsum    = (float*)alloc((size_t)N_GRAPHS * 128 * 4);
  int*   gcnt    = (int*)alloc((size_t)N_GRAPHS * 4);
  char* zend = (char*)alloc(0);

  hipMemsetAsync(zbase, 0, (size_t)(zend - zbase), stream);

  wconv<<<17 * 64, 256, 0, stream>>>(Wh_emb, We_emb, WA, WB, WC, WD, WE, Wt);

  hist_kernel<<<(N_EDGES + 255) / 256, 256, 0, stream>>>(dst, cnt, N_EDGES);
  scan_kernel<<<1, 1024, 0, stream>>>(cnt, start, cursor, N_NODES, N_EDGES);
  scatter_kernel<<<(N_EDGES + 255) / 256, 256, 0, stream>>>(dst, src, snorm_e, cursor,
                                                            csr, csrc, cdst, csne, N_EDGES);

  const int gbN = (N_NODES + 63) / 64;   // 469
  const int gbE = N_EDGES / 64;          // 7500
  const unsigned SH0 = 49664;            // LMODE 0: W + TB
  const unsigned SH2 = 32768;            // LMODE 2/3: W/TB overlay

  for (int l = 0; l < N_LAYERS; ++l) {
    const size_t bOff = (size_t)l * 128;
    const int doE = (l < N_LAYERS - 1) ? 1 : 0;
    // node GEMMs: Ah,Bh,Dh,Eh (+ emb chain at l=0, BN fold at l>=1)
    {
      GemmArgs g{};
      g.Wt[0] = Wt + (size_t)(2 + l)  * 16384; g.bias[0] = bA + bOff; g.out[0] = Ah;
      g.Wt[1] = Wt + (size_t)(5 + l)  * 16384; g.bias[1] = bB + bOff; g.out[1] = Bh;
      g.Wt[2] = Wt + (size_t)(11 + l) * 16384; g.bias[2] = bD + bOff; g.out[2] = Dh;
      g.Wt[3] = Wt + (size_t)(14 + l) * 16384; g.bias[3] = bE + bOff; g.out[3] = Eh;
      if (l == 0)
        gemm_mm<4, 2><<<gbN, 256, 0, stream>>>(h_in, g, N_NODES, nullptr, nullptr, hbuf,
                                               Wt + 0 * 16384, bh_emb);
      else
        gemm_mm<4, 1><<<gbN, 256, 0, stream>>>(hbuf, g, N_NODES, tbuf, pqh, hbuf,
                                               nullptr, nullptr);
    }
    // edge kernel (CSR order; e BN-apply of prev layer folded into A-load)
    const unsigned short* WtC = Wt + (size_t)(8 + l) * 16384;
    if (l == 0)
      edge_kern<0><<<gbE, 256, SH0, stream>>>(e_in, csr, ebuf, enew, Wt + 1 * 16384, be_emb,
                                              WtC, bC + bOff, Dh, Eh, csrc, cdst, csne, nullptr);
    else if (l == 1)
      edge_kern<2><<<gbE, 256, SH2, stream>>>(nullptr, nullptr, ebuf, enew, nullptr, nullptr,
                                              WtC, bC + bOff, Dh, Eh, csrc, cdst, csne, pqe);
    else
      edge_kern<3><<<gbE, 256, SH2, stream>>>(nullptr, nullptr, ebuf, enew, nullptr, nullptr,
                                              WtC, bC + bOff, Dh, Eh, csrc, cdst, csne, pqe);
    // gated reduce + BN stats (streaming enew), then tiny finalize dispatch
    if (doE)
      aggregate<1><<<N_NODES / 16, 256, 0, stream>>>(enew, Bh, Ah, snorm_n, start, csrc, csne,
                                                     tbuf, statrep);
    else
      aggregate<0><<<N_NODES / 16, 256, 0, stream>>>(enew, Bh, Ah, snorm_n, start, csrc, csne,
                                                     tbuf, statrep);
    finalize_kernel<<<1, 128, 0, stream>>>(statrep, pqh, pqe, gn_h + bOff, bt_h + bOff,
                                           gn_e + bOff, bt_e + bOff,
                                           1.f / N_NODES, 1.f / N_EDGES, doE);
  }

  // readout (final h-apply folded)
  readout_scatter<<<(N_NODES + 255) / 256, 128, 0, stream>>>(hbuf, tbuf, pqh, gid, gsum, gcnt, N_NODES);
  readout_final<<<N_GRAPHS, 128, 0, stream>>>(gsum, gcnt, Wr, br, out);
}

// Round 12
// 866.412 us; speedup vs baseline: 1.0862x; 1.0445x over previous
//
#include <hip/hip_runtime.h>
#include <cstdint>
#include <cstddef>

#define N_NODES  30000
#define N_EDGES  480000
#define N_LAYERS 3
#define N_GRAPHS 64
#define N_CLASS  10
#define NREP     32

typedef __attribute__((ext_vector_type(8))) short short8v;   // 8 bf16 (4 VGPR)
typedef __attribute__((ext_vector_type(4))) float f32x4;

__device__ __forceinline__ unsigned short f2bf(float x) {
  union { float f; unsigned u; } v; v.f = x;
  unsigned r = v.u + 0x7FFFu + ((v.u >> 16) & 1u);   // RNE
  return (unsigned short)(r >> 16);
}
__device__ __forceinline__ float bf2f(unsigned short h) {
  union { unsigned u; float f; } v; v.u = ((unsigned)h) << 16;
  return v.f;
}
// XOR-swizzle for the [128 rows x 256B] W tile (guide §6 G4).
__device__ __forceinline__ int swzW(int row, int off16) {
  return (row << 8) | (off16 ^ ((row & 7) << 4));
}

// ============ weight convert + transpose: Wt[mi][n][k] = bf16(W[k][n]) ======
__global__ void wconv(const float* __restrict__ Wh, const float* __restrict__ We,
                      const float* __restrict__ WA, const float* __restrict__ WB,
                      const float* __restrict__ WC, const float* __restrict__ WD,
                      const float* __restrict__ WE, unsigned short* __restrict__ Wt)
{
  const int mi  = blockIdx.x >> 6;
  const int idx = (blockIdx.x & 63) * 256 + threadIdx.x;   // 0..16383
  const float* src;
  if      (mi == 0) src = Wh;
  else if (mi == 1) src = We;
  else if (mi < 5)  src = WA + (size_t)(mi - 2) * 16384;
  else if (mi < 8)  src = WB + (size_t)(mi - 5) * 16384;
  else if (mi < 11) src = WC + (size_t)(mi - 8) * 16384;
  else if (mi < 14) src = WD + (size_t)(mi - 11) * 16384;
  else              src = WE + (size_t)(mi - 14) * 16384;
  const int k = idx >> 7, n = idx & 127;
  Wt[(size_t)mi * 16384 + (size_t)n * 128 + k] = f2bf(src[idx]);
}

// ============ node GEMM: 2 matrices per block, blockIdx.y = matrix pair =====
// AMODE 1: A = hcur + relu(tbuf*P+Q); y==0 block writes hnxt (ping-pong)
// AMODE 2: CHAIN — A = bf16(h_in_fp32 @ WtX + biasX); y==0 writes hout
struct GemmArgs {
  const unsigned short* Wt[4];
  const float* bias[4];
  unsigned short* out[4];
};

template<int NMAT, int AMODE>
__global__ __launch_bounds__(256)
void gemm_mm(const void* __restrict__ Ap, GemmArgs g, int M,
             const unsigned short* __restrict__ tb, const float2* __restrict__ pqh,
             unsigned short* __restrict__ hout,
             const unsigned short* __restrict__ WtX, const float* __restrict__ biasX)
{
  __shared__ __align__(16) unsigned char WL[32768];
  unsigned short* Wl = (unsigned short*)WL;
  const int t = threadIdx.x;
  const int mbase = blockIdx.y * NMAT;
  const bool wr0 = (blockIdx.y == 0);
  const int w = t >> 6, l = t & 63;
  const int lr = l & 15, lkb = (l >> 4) * 8;
  const int r0 = blockIdx.x * 64;
  const bool vrow = (r0 + w * 16 + lr) < M;
  int arow = r0 + w * 16 + lr; if (arow >= M) arow = M - 1;

  short8v a[4];
  if (AMODE == 2) {
#pragma unroll
    for (int p = 0; p < 8; ++p) {
      const int ci = t + p * 256;
      *(short8v*)(WL + swzW(ci >> 4, (ci & 15) * 16)) = *(const short8v*)(WtX + (size_t)ci * 8);
    }
    const float* A = (const float*)Ap;
#pragma unroll
    for (int kk = 0; kk < 4; ++kk) {
      const float* p = A + (size_t)arow * 128 + kk * 32 + lkb;
      const float4 u = *(const float4*)p;
      const float4 v = *(const float4*)(p + 4);
      short8v av;
      av[0]=f2bf(u.x); av[1]=f2bf(u.y); av[2]=f2bf(u.z); av[3]=f2bf(u.w);
      av[4]=f2bf(v.x); av[5]=f2bf(v.y); av[6]=f2bf(v.z); av[7]=f2bf(v.w);
      a[kk] = av;
    }
    __syncthreads();
    f32x4 acc[8];
#pragma unroll
    for (int ct = 0; ct < 8; ++ct) acc[ct] = (f32x4){0.f, 0.f, 0.f, 0.f};
#pragma unroll
    for (int kk = 0; kk < 4; ++kk)
#pragma unroll
      for (int ct = 0; ct < 8; ++ct) {
        const short8v b = *(const short8v*)(WL + swzW(ct * 16 + lr, kk * 64 + (l >> 4) * 16));
        acc[ct] = __builtin_amdgcn_mfma_f32_16x16x32_bf16(a[kk], b, acc[ct], 0, 0, 0);
      }
    __syncthreads();
#pragma unroll
    for (int ct = 0; ct < 8; ++ct) {
      const float bb = biasX[ct * 16 + lr];
#pragma unroll
      for (int q = 0; q < 4; ++q)
        Wl[(w * 16 + (l >> 4) * 4 + q) * 136 + ct * 16 + lr] = f2bf(acc[ct][q] + bb);
    }
    __syncthreads();
#pragma unroll
    for (int kk = 0; kk < 4; ++kk) {
      a[kk] = *(const short8v*)(Wl + (w * 16 + lr) * 136 + kk * 32 + lkb);
      if (wr0 && vrow) *(short8v*)(hout + (size_t)arow * 128 + kk * 32 + lkb) = a[kk];
    }
  } else if (AMODE == 1) {
    const unsigned short* A = (const unsigned short*)Ap;
#pragma unroll
    for (int kk = 0; kk < 4; ++kk) {
      const short8v tv = *(const short8v*)(tb + (size_t)arow * 128 + kk * 32 + lkb);
      const short8v hr = *(const short8v*)(A + (size_t)arow * 128 + kk * 32 + lkb);
      short8v av;
#pragma unroll
      for (int j = 0; j < 8; ++j) {
        const float2 PQ = pqh[kk * 32 + lkb + j];
        const float x = bf2f((unsigned short)tv[j]) * PQ.x + PQ.y;
        av[j] = (short)f2bf(bf2f((unsigned short)hr[j]) + fmaxf(x, 0.f));
      }
      a[kk] = av;
      if (wr0 && vrow) *(short8v*)(hout + (size_t)arow * 128 + kk * 32 + lkb) = av;
    }
  } else {
    const unsigned short* A = (const unsigned short*)Ap;
#pragma unroll
    for (int kk = 0; kk < 4; ++kk)
      a[kk] = *(const short8v*)(A + (size_t)arow * 128 + kk * 32 + lkb);
  }

#pragma unroll
  for (int m = 0; m < NMAT; ++m) {
    if (m || AMODE == 2) __syncthreads();
#pragma unroll
    for (int p = 0; p < 8; ++p) {
      const int ci = t + p * 256;
      *(short8v*)(WL + swzW(ci >> 4, (ci & 15) * 16)) = *(const short8v*)(g.Wt[mbase + m] + (size_t)ci * 8);
    }
    __syncthreads();
    f32x4 acc[8];
#pragma unroll
    for (int ct = 0; ct < 8; ++ct) acc[ct] = (f32x4){0.f, 0.f, 0.f, 0.f};
#pragma unroll
    for (int kk = 0; kk < 4; ++kk)
#pragma unroll
      for (int ct = 0; ct < 8; ++ct) {
        const short8v b = *(const short8v*)(WL + swzW(ct * 16 + lr, kk * 64 + (l >> 4) * 16));
        acc[ct] = __builtin_amdgcn_mfma_f32_16x16x32_bf16(a[kk], b, acc[ct], 0, 0, 0);
      }
    __syncthreads();
#pragma unroll
    for (int ct = 0; ct < 8; ++ct) {
      const float bb = g.bias[mbase + m][ct * 16 + lr];
#pragma unroll
      for (int q = 0; q < 4; ++q)
        Wl[(w * 16 + (l >> 4) * 4 + q) * 136 + ct * 16 + lr] = f2bf(acc[ct][q] + bb);
    }
    __syncthreads();
    unsigned short* out = g.out[mbase + m];
#pragma unroll
    for (int p = 0; p < 4; ++p) {
      const int ci = t + p * 256;
      const int rr = ci >> 4, co = (ci & 15) * 8;
      const int grow = r0 + rr;
      if (grow < M)
        *(short8v*)(out + (size_t)grow * 128 + co) = *(const short8v*)(Wl + rr * 136 + co);
    }
  }
}

// ============ edge kernel, 64 rows/block; edge tensors in CSR order =========
// (unchanged from R11: gather prefetch before MFMA, TB/SM overlay for MID/LAST)
template<int LMODE>
__global__ __launch_bounds__(256)
void edge_kern(const float* __restrict__ e_in, const int* __restrict__ csr,
               unsigned short* __restrict__ eres, unsigned short* __restrict__ enew,
               const unsigned short* __restrict__ WtEmb, const float* __restrict__ bEmb,
               const unsigned short* __restrict__ WtC, const float* __restrict__ bC,
               const unsigned short* __restrict__ Dh, const unsigned short* __restrict__ Eh,
               const int* __restrict__ csrc, const int* __restrict__ cdst,
               const float* __restrict__ csne, const float2* __restrict__ pq)
{
  extern __shared__ __align__(16) char smem[];
  char* SM = smem;                                          // 32768 B: swizzled W
  unsigned short* TB = (unsigned short*)((LMODE == 0) ? (smem + 32768) : smem);
  const int t = threadIdx.x;
  const int w = t >> 6, l = t & 63;
  const int lr = l & 15, lkb = (l >> 4) * 8;
  const int r0 = blockIdx.x * 64;                           // E % 64 == 0
  const int pos = r0 + w * 16 + lr;

  short8v a[4];
  f32x4 acc[8];
  short8v dpre[4], epre[4];                                 // prefetched gathers

  if (LMODE == 0) {
#pragma unroll
    for (int p = 0; p < 8; ++p) {
      const int ci = t + p * 256;
      *(short8v*)(SM + swzW(ci >> 4, (ci & 15) * 16)) = *(const short8v*)(WtEmb + (size_t)ci * 8);
    }
#pragma unroll
    for (int p = 0; p < 4; ++p) {
      const int ci = t + p * 256;
      const int rr = ci >> 4, co = (ci & 15) * 8;
      const float* sp = e_in + (size_t)csr[r0 + rr] * 128 + co;
      const float4 u = *(const float4*)sp;
      const float4 v = *(const float4*)(sp + 4);
      short8v av;
      av[0]=f2bf(u.x); av[1]=f2bf(u.y); av[2]=f2bf(u.z); av[3]=f2bf(u.w);
      av[4]=f2bf(v.x); av[5]=f2bf(v.y); av[6]=f2bf(v.z); av[7]=f2bf(v.w);
      *(short8v*)(TB + rr * 132 + co) = av;
    }
    __syncthreads();
#pragma unroll
    for (int kk = 0; kk < 4; ++kk)
      a[kk] = *(const short8v*)(TB + (w * 16 + lr) * 132 + kk * 32 + lkb);
#pragma unroll
    for (int ct = 0; ct < 8; ++ct) acc[ct] = (f32x4){0.f, 0.f, 0.f, 0.f};
#pragma unroll
    for (int kk = 0; kk < 4; ++kk)
#pragma unroll
      for (int ct = 0; ct < 8; ++ct) {
        const short8v b = *(const short8v*)(SM + swzW(ct * 16 + lr, kk * 64 + (l >> 4) * 16));
        acc[ct] = __builtin_amdgcn_mfma_f32_16x16x32_bf16(a[kk], b, acc[ct], 0, 0, 0);
      }
    __syncthreads();
#pragma unroll
    for (int ct = 0; ct < 8; ++ct) {
      const float bb = bEmb[ct * 16 + lr];
#pragma unroll
      for (int q = 0; q < 4; ++q)
        TB[(w * 16 + (l >> 4) * 4 + q) * 132 + ct * 16 + lr] = f2bf(acc[ct][q] + bb);
    }
#pragma unroll
    for (int p = 0; p < 8; ++p) {
      const int ci = t + p * 256;
      *(short8v*)(SM + swzW(ci >> 4, (ci & 15) * 16)) = *(const short8v*)(WtC + (size_t)ci * 8);
    }
    __syncthreads();
#pragma unroll
    for (int kk = 0; kk < 4; ++kk) {
      a[kk] = *(const short8v*)(TB + (w * 16 + lr) * 132 + kk * 32 + lkb);
      *(short8v*)(eres + (size_t)pos * 128 + kk * 32 + lkb) = a[kk];
    }
  } else {
#pragma unroll
    for (int p = 0; p < 8; ++p) {
      const int ci = t + p * 256;
      *(short8v*)(SM + swzW(ci >> 4, (ci & 15) * 16)) = *(const short8v*)(WtC + (size_t)ci * 8);
    }
    const float sn = csne[pos];
    short8v ep[4], er[4];
#pragma unroll
    for (int kk = 0; kk < 4; ++kk) {
      ep[kk] = *(const short8v*)(enew + (size_t)pos * 128 + kk * 32 + lkb);
      er[kk] = *(const short8v*)(eres + (size_t)pos * 128 + kk * 32 + lkb);
    }
#pragma unroll
    for (int kk = 0; kk < 4; ++kk) {
      short8v av;
#pragma unroll
      for (int j = 0; j < 8; ++j) {
        const float2 PQ = pq[kk * 32 + lkb + j];     // global, L1-broadcast
        const float x = bf2f((unsigned short)ep[kk][j]) * sn * PQ.x + PQ.y;
        av[j] = (short)f2bf(bf2f((unsigned short)er[kk][j]) + fmaxf(x, 0.f));
      }
      a[kk] = av;
      if (LMODE == 2)
        *(short8v*)(eres + (size_t)pos * 128 + kk * 32 + lkb) = av;
    }
    __syncthreads();                                 // W staged
  }

  // issue epilogue gathers NOW; latency hides under the MFMA loop
#pragma unroll
  for (int p = 0; p < 4; ++p) {
    const int ci = t + p * 256;
    const int rr = ci >> 4, co = (ci & 15) * 8;
    const int pp = r0 + rr;
    dpre[p] = *(const short8v*)(Dh + (size_t)csrc[pp] * 128 + co);
    epre[p] = *(const short8v*)(Eh + (size_t)cdst[pp] * 128 + co);
  }

#pragma unroll
  for (int ct = 0; ct < 8; ++ct) acc[ct] = (f32x4){0.f, 0.f, 0.f, 0.f};
#pragma unroll
  for (int kk = 0; kk < 4; ++kk)
#pragma unroll
    for (int ct = 0; ct < 8; ++ct) {
      const short8v b = *(const short8v*)(SM + swzW(ct * 16 + lr, kk * 64 + (l >> 4) * 16));
      acc[ct] = __builtin_amdgcn_mfma_f32_16x16x32_bf16(a[kk], b, acc[ct], 0, 0, 0);
    }
  __syncthreads();                                   // all SM(W)/TB reads done
#pragma unroll
  for (int ct = 0; ct < 8; ++ct) {
    const float bb = bC[ct * 16 + lr];
#pragma unroll
    for (int q = 0; q < 4; ++q)
      TB[(w * 16 + (l >> 4) * 4 + q) * 132 + ct * 16 + lr] = f2bf(acc[ct][q] + bb);
  }
  __syncthreads();
#pragma unroll
  for (int p = 0; p < 4; ++p) {
    const int ci = t + p * 256;
    const int rr = ci >> 4, co = (ci & 15) * 8;
    const int pp = r0 + rr;
    const short8v ce = *(const short8v*)(TB + rr * 132 + co);
    short8v ov;
#pragma unroll
    for (int j = 0; j < 8; ++j)
      ov[j] = (short)f2bf(bf2f((unsigned short)ce[j]) + bf2f((unsigned short)dpre[p][j]) + bf2f((unsigned short)epre[p][j]));
    *(short8v*)(enew + (size_t)pp * 128 + co) = ov;
  }
}

// ============ CSR build =====================================================
__global__ void hist_kernel(const int* __restrict__ dst, int* __restrict__ cnt, int E)
{
  const int i = blockIdx.x * 256 + threadIdx.x;
  if (i < E) atomicAdd(&cnt[dst[i]], 1);
}

__global__ void scan_kernel(const int* __restrict__ cnt, int* __restrict__ start,
                            int* __restrict__ cursor, int n, int total)
{
  __shared__ int lds[1024];
  const int tid = threadIdx.x;
  const int chunk = (n + 1023) / 1024;
  const int lo = tid * chunk, hi = min(lo + chunk, n);
  int s = 0;
  for (int i = lo; i < hi; ++i) s += cnt[i];
  lds[tid] = s;
  __syncthreads();
  for (int off = 1; off < 1024; off <<= 1) {
    const int v = (tid >= off) ? lds[tid - off] : 0;
    __syncthreads();
    lds[tid] += v;
    __syncthreads();
  }
  int run = (tid == 0) ? 0 : lds[tid - 1];
  for (int i = lo; i < hi; ++i) { start[i] = run; cursor[i] = run; run += cnt[i]; }
  if (tid == 0) start[n] = total;
}

__global__ void scatter_kernel(const int* __restrict__ dst, const int* __restrict__ src,
                               const float* __restrict__ sne, int* __restrict__ cursor,
                               int* __restrict__ csr, int* __restrict__ csrc,
                               int* __restrict__ cdst, float* __restrict__ csne, int E)
{
  const int i = blockIdx.x * 256 + threadIdx.x;
  if (i < E) {
    const int p = atomicAdd(&cursor[dst[i]], 1);
    csr[p] = i; csrc[p] = src[i]; cdst[p] = dst[i]; csne[p] = sne[i];
  }
}

// ============ aggregate: 1 wave = 1 node, 4 parallel edge sub-chains ========
// lanes: sub = lane>>4 walks edges s0+sub, s0+sub+4, ...; q = lane&15 = col
// chunk. Butterfly shfl_xor(16,32) combines sub-chains -> 4x shorter serial
// dependency than the single-chain version.
template<int DOE>
__global__ __launch_bounds__(256)
void aggregate(const unsigned short* __restrict__ enew, const unsigned short* __restrict__ Bh,
               const unsigned short* __restrict__ Ah, const float* __restrict__ snorm_n,
               const int* __restrict__ start, const int* __restrict__ csrc,
               const float* __restrict__ csne,
               unsigned short* __restrict__ tbuf, float* __restrict__ statrep)
{
  __shared__ float2 red[4][132];
  __shared__ float2 redE[4][132];
  const int t = threadIdx.x;
  const int wv = t >> 6;                 // wave id = node slot (4 nodes/block)
  const int lane = t & 63;
  const int sub = lane >> 4;             // sub-chain 0..3
  const int q = lane & 15;               // col chunk (8 bf16 = 16 B)
  const int v = blockIdx.x * 4 + wv;     // N % 4 == 0
  const int s0 = start[v], s1 = start[v + 1];
  float num[8] = {0,0,0,0,0,0,0,0}, den[8] = {0,0,0,0,0,0,0,0};
  float psE[8] = {0,0,0,0,0,0,0,0}, pqE[8] = {0,0,0,0,0,0,0,0};

  int i = s0 + sub;
  float sn = 0.f;
  short8v ev = {}, bv = {};
  if (i < s1) {
    if (DOE) sn = csne[i];
    ev = *(const short8v*)(enew + (size_t)i * 128 + q * 8);
    bv = *(const short8v*)(Bh + (size_t)csrc[i] * 128 + q * 8);
  }
  for (; i < s1; i += 4) {
    float snn = 0.f;
    short8v evn = {}, bvn = {};
    if (i + 4 < s1) {                    // prefetch next edge of this sub-chain
      if (DOE) snn = csne[i + 4];
      evn = *(const short8v*)(enew + (size_t)(i + 4) * 128 + q * 8);
      bvn = *(const short8v*)(Bh + (size_t)csrc[i + 4] * 128 + q * 8);
    }
#pragma unroll
    for (int j = 0; j < 8; ++j) {
      const float en = bf2f((unsigned short)ev[j]);
      const float sg = 1.f / (1.f + __expf(-en));
      num[j] = fmaf(sg, bf2f((unsigned short)bv[j]), num[j]);
      den[j] += sg;
      if (DOE) { const float tv = en * sn; psE[j] += tv; pqE[j] = fmaf(tv, tv, pqE[j]); }
    }
    ev = evn; bv = bvn; sn = snn;
  }
  // combine the 4 sub-chains (butterfly over lane bits 16 and 32)
#pragma unroll
  for (int j = 0; j < 8; ++j) {
    num[j] += __shfl_xor(num[j], 16, 64);
    num[j] += __shfl_xor(num[j], 32, 64);
    den[j] += __shfl_xor(den[j], 16, 64);
    den[j] += __shfl_xor(den[j], 32, 64);
    if (DOE) {
      psE[j] += __shfl_xor(psE[j], 16, 64);
      psE[j] += __shfl_xor(psE[j], 32, 64);
      pqE[j] += __shfl_xor(pqE[j], 16, 64);
      pqE[j] += __shfl_xor(pqE[j], 32, 64);
    }
  }
  if (sub == 0) {                        // lanes 0..15 finalize node v
    const float snv = snorm_n[v];
    const short8v av = *(const short8v*)(Ah + (size_t)v * 128 + q * 8);
    short8v tout;
#pragma unroll
    for (int j = 0; j < 8; ++j) {
      const float hv = (bf2f((unsigned short)av[j]) + num[j] / (den[j] + 1e-6f)) * snv;
      tout[j] = (short)f2bf(hv);
      red[wv][q * 8 + j] = make_float2(hv, hv * hv);
      if (DOE) redE[wv][q * 8 + j] = make_float2(psE[j], pqE[j]);
    }
    *(short8v*)(tbuf + (size_t)v * 128 + q * 8) = tout;
  }
  __syncthreads();
  float* rep = statrep + (size_t)(blockIdx.x & (NREP - 1)) * 512;
  if (t < 128) {
    float s = 0.f, qq = 0.f;
#pragma unroll
    for (int gg = 0; gg < 4; ++gg) { s += red[gg][t].x; qq += red[gg][t].y; }
    atomicAdd(rep + t, s); atomicAdd(rep + 128 + t, qq);
    if (DOE) {
      float se = 0.f, qe = 0.f;
#pragma unroll
      for (int gg = 0; gg < 4; ++gg) { se += redE[gg][t].x; qe += redE[gg][t].y; }
      atomicAdd(rep + 256 + t, se); atomicAdd(rep + 384 + t, qe);
    }
  }
}

// ============ finalize (separate dispatch = cross-block fence) ==============
__global__ void finalize_kernel(float* __restrict__ rep, float2* __restrict__ pqh,
                                float2* __restrict__ pqe,
                                const float* __restrict__ gn_h_l, const float* __restrict__ bt_h_l,
                                const float* __restrict__ gn_e_l, const float* __restrict__ bt_e_l,
                                float invN, float invE, int doE)
{
  const int c = threadIdx.x;
  float sH = 0.f, qH = 0.f, sE = 0.f, qE = 0.f;
  for (int r = 0; r < NREP; ++r) {
    float* p = rep + (size_t)r * 512;
    sH += p[c]; qH += p[128 + c]; sE += p[256 + c]; qE += p[384 + c];
    p[c] = 0.f; p[128 + c] = 0.f; p[256 + c] = 0.f; p[384 + c] = 0.f;
  }
  const float muH = sH * invN;
  const float vH  = fmaxf(qH * invN - muH * muH, 0.f);
  const float PH  = rsqrtf(vH + 1e-5f) * gn_h_l[c];
  pqh[c] = make_float2(PH, bt_h_l[c] - muH * PH);
  if (doE) {
    const float muE = sE * invE;
    const float vE  = fmaxf(qE * invE - muE * muE, 0.f);
    const float PE  = rsqrtf(vE + 1e-5f) * gn_e_l[c];
    pqe[c] = make_float2(PE, bt_e_l[c] - muE * PE);
  }
}

// ============ readout (h-apply of last layer folded in) =====================
__global__ void readout_scatter(const unsigned short* __restrict__ h, const unsigned short* __restrict__ tb,
                                const float2* __restrict__ pqh, const int* __restrict__ gid,
                                float* __restrict__ gsum, int* __restrict__ gcnt, int N)
{
  const int c = threadIdx.x;            // 128
  const float2 PQ = pqh[c];
  const int row0 = blockIdx.x * 256;
  int cur = -1, cnt = 0;
  float s = 0.f;
  for (int r = 0; r < 256; ++r) {
    const int v = row0 + r;
    if (v >= N) break;
    const int g = gid[v];
    if (g != cur) {
      if (cur >= 0) {
        atomicAdd(&gsum[(size_t)cur * 128 + c], s);
        if (c == 0) atomicAdd(&gcnt[cur], cnt);
      }
      cur = g; s = 0.f; cnt = 0;
    }
    s += bf2f(h[(size_t)v * 128 + c]) + fmaxf(bf2f(tb[(size_t)v * 128 + c]) * PQ.x + PQ.y, 0.f);
    ++cnt;
  }
  if (cur >= 0) {
    atomicAdd(&gsum[(size_t)cur * 128 + c], s);
    if (c == 0) atomicAdd(&gcnt[cur], cnt);
  }
}

__global__ void readout_final(const float* __restrict__ gsum, const int* __restrict__ gcnt,
                              const float* __restrict__ Wr, const float* __restrict__ br,
                              float* __restrict__ out)
{
  const int g = blockIdx.x;
  const int t = threadIdx.x;            // 128
  __shared__ float hg[128];
  const float cnt = fmaxf((float)gcnt[g], 1.f);
  hg[t] = gsum[(size_t)g * 128 + t] / cnt;
  __syncthreads();
  if (t < N_CLASS) {
    float acc = br[t];
    for (int k = 0; k < 128; ++k) acc = fmaf(hg[k], Wr[k * N_CLASS + t], acc);
    out[g * N_CLASS + t] = acc;
  }
}

// ============ launcher ======================================================
extern "C" void kernel_launch(void* const* d_in, const int* in_sizes, int n_in,
                              void* d_out, int out_size, void* d_ws, size_t ws_size,
                              hipStream_t stream)
{
  const float* h_in    = (const float*)d_in[0];
  const float* e_in    = (const float*)d_in[1];
  const float* snorm_n = (const float*)d_in[2];
  const float* snorm_e = (const float*)d_in[3];
  const int*   src     = (const int*)d_in[4];
  const int*   dst     = (const int*)d_in[5];
  const int*   gid     = (const int*)d_in[6];
  const float* Wh_emb  = (const float*)d_in[7];
  const float* bh_emb  = (const float*)d_in[8];
  const float* We_emb  = (const float*)d_in[9];
  const float* be_emb  = (const float*)d_in[10];
  const float* WA = (const float*)d_in[11]; const float* bA = (const float*)d_in[12];
  const float* WB = (const float*)d_in[13]; const float* bB = (const float*)d_in[14];
  const float* WC = (const float*)d_in[15]; const float* bC = (const float*)d_in[16];
  const float* WD = (const float*)d_in[17]; const float* bD = (const float*)d_in[18];
  const float* WE = (const float*)d_in[19]; const float* bE = (const float*)d_in[20];
  const float* gn_h = (const float*)d_in[21]; const float* bt_h = (const float*)d_in[22];
  const float* gn_e = (const float*)d_in[23]; const float* bt_e = (const float*)d_in[24];
  const float* Wr = (const float*)d_in[25]; const float* br = (const float*)d_in[26];
  float* out = (float*)d_out;
  (void)in_sizes; (void)n_in; (void)out_size; (void)ws_size;

  char* ws = (char*)d_ws;
  size_t off = 0;
  auto alloc = [&](size_t bytes) -> char* {
    off = (off + 255) & ~(size_t)255;
    char* p = ws + off;
    off += bytes;
    return p;
  };
  const size_t ND = (size_t)N_NODES * 128, ED = (size_t)N_EDGES * 128;
  unsigned short* hbufA = (unsigned short*)alloc(ND * 2);  // ping-pong h
  unsigned short* hbufB = (unsigned short*)alloc(ND * 2);
  unsigned short* ebuf  = (unsigned short*)alloc(ED * 2);  // residual e (CSR order)
  unsigned short* enew  = (unsigned short*)alloc(ED * 2);  // pre-BN e_new (CSR order)
  unsigned short* Ah   = (unsigned short*)alloc(ND * 2);
  unsigned short* Bh   = (unsigned short*)alloc(ND * 2);
  unsigned short* Dh   = (unsigned short*)alloc(ND * 2);
  unsigned short* Eh   = (unsigned short*)alloc(ND * 2);
  unsigned short* tbuf = (unsigned short*)alloc(ND * 2);   // pre-BN h_new (bf16)
  unsigned short* Wt   = (unsigned short*)alloc((size_t)17 * 16384 * 2);
  float2* pqh          = (float2*)alloc(128 * 8);
  float2* pqe          = (float2*)alloc(128 * 8);
  int* start  = (int*)alloc((size_t)(N_NODES + 1) * 4);
  int* cursor = (int*)alloc((size_t)N_NODES * 4);
  int* csr    = (int*)alloc((size_t)N_EDGES * 4);
  int* csrc   = (int*)alloc((size_t)N_EDGES * 4);
  int* cdst   = (int*)alloc((size_t)N_EDGES * 4);
  float* csne = (float*)alloc((size_t)N_EDGES * 4);
  // ---- contiguous zero-region (single memset) ----
  char* zbase = (char*)alloc(0);
  int*   cnt     = (int*)alloc((size_t)N_NODES * 4);
  float* statrep = (float*)alloc((size_t)NREP * 512 * 4);
  float* gsum    = (float*)alloc((size_t)N_GRAPHS * 128 * 4);
  int*   gcnt    = (int*)alloc((size_t)N_GRAPHS * 4);
  char* zend = (char*)alloc(0);

  hipMemsetAsync(zbase, 0, (size_t)(zend - zbase), stream);

  wconv<<<17 * 64, 256, 0, stream>>>(Wh_emb, We_emb, WA, WB, WC, WD, WE, Wt);

  hist_kernel<<<(N_EDGES + 255) / 256, 256, 0, stream>>>(dst, cnt, N_EDGES);
  scan_kernel<<<1, 1024, 0, stream>>>(cnt, start, cursor, N_NODES, N_EDGES);
  scatter_kernel<<<(N_EDGES + 255) / 256, 256, 0, stream>>>(dst, src, snorm_e, cursor,
                                                            csr, csrc, cdst, csne, N_EDGES);

  const int gbN = (N_NODES + 63) / 64;   // 469
  const int gbE = N_EDGES / 64;          // 7500
  const dim3 gN(gbN, 2);                 // 2 matrices per block
  const unsigned SH0 = 49664;            // LMODE 0: W + TB
  const unsigned SH2 = 32768;            // LMODE 2/3: W/TB overlay

  unsigned short* hcur = hbufA;
  unsigned short* hnxt = hbufB;

  for (int l = 0; l < N_LAYERS; ++l) {
    const size_t bOff = (size_t)l * 128;
    const int doE = (l < N_LAYERS - 1) ? 1 : 0;
    // node GEMMs: Ah,Bh | Dh,Eh split over blockIdx.y; ping-pong h buffers
    {
      GemmArgs g{};
      g.Wt[0] = Wt + (size_t)(2 + l)  * 16384; g.bias[0] = bA + bOff; g.out[0] = Ah;
      g.Wt[1] = Wt + (size_t)(5 + l)  * 16384; g.bias[1] = bB + bOff; g.out[1] = Bh;
      g.Wt[2] = Wt + (size_t)(11 + l) * 16384; g.bias[2] = bD + bOff; g.out[2] = Dh;
      g.Wt[3] = Wt + (size_t)(14 + l) * 16384; g.bias[3] = bE + bOff; g.out[3] = Eh;
      if (l == 0) {
        gemm_mm<2, 2><<<gN, 256, 0, stream>>>(h_in, g, N_NODES, nullptr, nullptr, hcur,
                                              Wt + 0 * 16384, bh_emb);
      } else {
        gemm_mm<2, 1><<<gN, 256, 0, stream>>>(hcur, g, N_NODES, tbuf, pqh, hnxt,
                                              nullptr, nullptr);
        unsigned short* tmp = hcur; hcur = hnxt; hnxt = tmp;
      }
    }
    // edge kernel (CSR order; e BN-apply of prev layer folded into A-load)
    const unsigned short* WtC = Wt + (size_t)(8 + l) * 16384;
    if (l == 0)
      edge_kern<0><<<gbE, 256, SH0, stream>>>(e_in, csr, ebuf, enew, Wt + 1 * 16384, be_emb,
                                              WtC, bC + bOff, Dh, Eh, csrc, cdst, csne, nullptr);
    else if (l == 1)
      edge_kern<2><<<gbE, 256, SH2, stream>>>(nullptr, nullptr, ebuf, enew, nullptr, nullptr,
                                              WtC, bC + bOff, Dh, Eh, csrc, cdst, csne, pqe);
    else
      edge_kern<3><<<gbE, 256, SH2, stream>>>(nullptr, nullptr, ebuf, enew, nullptr, nullptr,
                                              WtC, bC + bOff, Dh, Eh, csrc, cdst, csne, pqe);
    // gated reduce + BN stats (4 sub-chains/node), then tiny finalize dispatch
    if (doE)
      aggregate<1><<<N_NODES / 4, 256, 0, stream>>>(enew, Bh, Ah, snorm_n, start, csrc, csne,
                                                    tbuf, statrep);
    else
      aggregate<0><<<N_NODES / 4, 256, 0, stream>>>(enew, Bh, Ah, snorm_n, start, csrc, csne,
                                                    tbuf, statrep);
    finalize_kernel<<<1, 128, 0, stream>>>(statrep, pqh, pqe, gn_h + bOff, bt_h + bOff,
                                           gn_e + bOff, bt_e + bOff,
                                           1.f / N_NODES, 1.f / N_EDGES, doE);
  }

  // readout (final h-apply folded); hcur holds the post-layer-2 residual h
  readout_scatter<<<(N_NODES + 255) / 256, 128, 0, stream>>>(hcur, tbuf, pqh, gid, gsum, gcnt, N_NODES);
  readout_final<<<N_GRAPHS, 128, 0, stream>>>(gsum, gcnt, Wr, br, out);
}